// Round 11
// baseline (254.519 us; speedup 1.0000x reference)
//
#include <hip/hip_runtime.h>
#include <hip/hip_bf16.h>

typedef __bf16 bf16_t;
typedef __bf16 bf16x8 __attribute__((ext_vector_type(8)));
typedef float f32x4 __attribute__((ext_vector_type(4)));

#define B_ 8
#define LQ_ 2048
#define LK_ 2048
#define DM_ 1024

__device__ __forceinline__ void gload16(const void* g, void* l) {
  __builtin_amdgcn_global_load_lds(
      (const __attribute__((address_space(1))) void*)g,
      (__attribute__((address_space(3))) void*)l, 16, 0, 0);
}

// ---------------- f32 -> bf16 convert (vectorized) ----------------
__global__ __launch_bounds__(256) void cvt_bf16_kernel(
    const float* __restrict__ in, bf16_t* __restrict__ out, int n8) {
  int stride = gridDim.x * blockDim.x;
  for (int i = blockIdx.x * blockDim.x + threadIdx.x; i < n8; i += stride) {
    const float4* p = reinterpret_cast<const float4*>(in) + (size_t)i * 2;
    float4 a = p[0], b = p[1];
    bf16x8 o;
    o[0] = (bf16_t)a.x; o[1] = (bf16_t)a.y; o[2] = (bf16_t)a.z; o[3] = (bf16_t)a.w;
    o[4] = (bf16_t)b.x; o[5] = (bf16_t)b.y; o[6] = (bf16_t)b.z; o[7] = (bf16_t)b.w;
    *reinterpret_cast<bf16x8*>(out + (size_t)i * 8) = o;
  }
}

// ---------------- V [B][LK][DM] f32 -> Vt [B][DM][LK] bf16 ----------------
__global__ __launch_bounds__(256) void transpose_v(
    const float* __restrict__ V, bf16_t* __restrict__ Vt) {
  __shared__ bf16_t tile[64][65];
  int b = blockIdx.z;
  int k0 = blockIdx.x * 64;
  int d0 = blockIdx.y * 64;
  int r = threadIdx.x >> 6;
  int c = threadIdx.x & 63;
  const float* src = V + ((size_t)b * LK_ + k0) * DM_ + d0;
#pragma unroll
  for (int i = 0; i < 64; i += 4)
    tile[r + i][c] = (bf16_t)src[(size_t)(r + i) * DM_ + c];
  __syncthreads();
  bf16_t* dst = Vt + ((size_t)b * DM_ + d0) * LK_ + k0;
#pragma unroll
  for (int i = 0; i < 64; i += 4)
    dst[(size_t)(r + i) * LK_ + c] = tile[c][r + i];
}

// ---------------- rowsum partials -> inverse rowsums ----------------
__global__ __launch_bounds__(256) void rowsum_inv_kernel(
    const float* __restrict__ pbuf, float* __restrict__ rinv) {
  int R = blockIdx.x * 256 + threadIdx.x;  // 0..16383
  int b = R >> 11, row = R & 2047;
  float s = 0.f;
#pragma unroll
  for (int cb = 0; cb < 8; ++cb)
    s += pbuf[((long)b * 8 + cb) * 2048 + row];
  rinv[R] = 1.0f / s;
}

// ------------- 256x256 READ-AHEAD GEMM, C = A * B^T -------------
// r10 post-mortem: all prior structures issued ds_reads and consumed them
// with MFMA in the SAME barrier interval -> CU-level LDS-drain and MFMA
// alternate (additive, ~35% MfmaUtil invariant). This kernel pipelines at
// REGISTER level: interval t = {issue ds_reads tile t+1 into other reg set;
// stage tile t+3; MFMA tile t from resident regs (no lgkm wait); vmcnt(4);
// lgkm0; barrier}. LDS drains under MFMA.
// BK=32, 4 LDS buffers (4x32KB=128KB), linear layout (r2: 0 conflicts),
// 8 waves 2Mx4N, wave tile 128x64, 32 MFMA/tile/wave, reg sets aA/bA,aB/bB.
// Hazards: STG(t+3) overwrites tile t-1 buf (reads drained 2 barriers ago);
// reads of t+1 staged at t-2, vmcnt-drained end of t-1; all waits drain
// loads >=1 interval old; drain-before-barrier, read-after-barrier.
// MODE 0: C bf16, C += bias[col]                    (Q projection)
// MODE 1: C bf16, C = exp(C/32 + mask[b][col]); + rowsum partials->extra2
// MODE 2: C f32,  C = acc * rinv[b][row]            (extra = rinv)
#define BARX __builtin_amdgcn_s_barrier()
#define PRIO1 __builtin_amdgcn_s_setprio(1)
#define PRIO0 __builtin_amdgcn_s_setprio(0)
#define VM4 asm volatile("s_waitcnt vmcnt(4)" ::: "memory")
#define VM0 asm volatile("s_waitcnt vmcnt(0)" ::: "memory")
#define LGKM0 asm volatile("s_waitcnt lgkmcnt(0)" ::: "memory")

#define RDT(AS, BS, BUFE)                                                     \
  _Pragma("unroll") for (int m = 0; m < 8; ++m)                               \
      AS[m] = *(const bf16x8*)(pa + (BUFE) + m * 512);                        \
  _Pragma("unroll") for (int n = 0; n < 4; ++n)                               \
      BS[n] = *(const bf16x8*)(pb + (BUFE) + n * 512);

#define MQ32(AS, BS)                                                          \
  PRIO1;                                                                      \
  _Pragma("unroll") for (int m = 0; m < 8; ++m)                               \
  _Pragma("unroll") for (int n = 0; n < 4; ++n)                               \
      acc[m][n] = __builtin_amdgcn_mfma_f32_16x16x32_bf16(                    \
          AS[m], BS[n], acc[m][n], 0, 0, 0);                                  \
  PRIO0;

template <int MODE>
__global__ __launch_bounds__(512, 1) void gemm_bt(
    const bf16_t* __restrict__ A, const bf16_t* __restrict__ Bm,
    void* __restrict__ Cv, const float* __restrict__ extra,
    float* __restrict__ extra2,
    int N, int K, long sA, long sB, long sC, long sE, int gxs, int gys) {
  __shared__ bf16_t lds[65536];  // 4 bufs x (A 8192 + B 8192) elems = 128 KiB

  const int tid = threadIdx.x;
  const int lane = tid & 63;
  const int wave = tid >> 6;

  // XCD-aware bijective block swizzle (gridDim.x % 8 == 0 for all our grids)
  const int nwg = gridDim.x;
  const int lin = blockIdx.x;
  const int cpx = nwg >> 3;
  const int swz = (lin & 7) * cpx + (lin >> 3);
  const int gx = 1 << gxs;
  const int bx = swz & (gx - 1);
  const int rem = swz >> gxs;
  const int by = rem & ((1 << gys) - 1);
  const int bz = rem >> gys;

  const bf16_t* Ab = A + (long)bz * sA + (long)(by * 256) * K;
  const bf16_t* Bb = Bm + (long)bz * sB + (long)(bx * 256) * K;

  // staging: thread tid handles chunks tid and tid+512 of each matrix.
  // chunk ch: row = ch>>2, col = (ch&3)*8 within the 256x32 tile (linear).
  const int rA = tid >> 2;             // 0..127
  const int cA = (tid & 3) * 8;

  auto STG = [&](int t) {
    const int bufe = (t & 3) * 16384;
    const bf16_t* gA = Ab + (long)rA * K + t * 32 + cA;
    const bf16_t* gB = Bb + (long)rA * K + t * 32 + cA;
    bf16_t* l = lds + bufe + tid * 8;
    gload16(gA, l);
    gload16(gA + (long)128 * K, l + 4096);
    gload16(gB, l + 8192);
    gload16(gB + (long)128 * K, l + 12288);
  };

  // fragment read geometry (linear, BK=32: row stride 32 elems)
  const int wr = wave >> 2;   // 0..1
  const int wc = wave & 3;    // 0..3
  const int fr = lane & 15;
  const int g8 = (lane >> 4) * 8;
  const bf16_t* pa = lds + (wr * 128 + fr) * 32 + g8;          // + m*512
  const bf16_t* pb = lds + 8192 + (wc * 64 + fr) * 32 + g8;    // + n*512

  f32x4 acc[8][4] = {};
  bf16x8 aA[8], bA[4], aB[8], bB[4];

  const int NT = K >> 5;  // K-tiles (BK=32); multiple of 4 here (32 or 64)

  // prologue: stage t0,t1,t2; drain t0,t1 (keep t2 in flight); read tile0.
  STG(0); STG(1); STG(2);
  VM4; BARX;
  RDT(aA, bA, 0);

  for (int j = 0; j < NT; j += 4) {
    // ---- t = j: consume A-set, read tile j+1 -> B-set (buf1) ----
    {
      const int t = j;
      if (t + 1 < NT) { RDT(aB, bB, 16384); }
      if (t + 3 < NT) STG(t + 3);
      MQ32(aA, bA);
      if (t + 3 < NT) { VM4; } else { VM0; }
      LGKM0; BARX;
    }
    // ---- t = j+1: consume B-set, read tile j+2 -> A-set (buf2) ----
    {
      const int t = j + 1;
      if (t + 1 < NT) { RDT(aA, bA, 32768); }
      if (t + 3 < NT) STG(t + 3);
      MQ32(aB, bB);
      if (t + 3 < NT) { VM4; } else { VM0; }
      LGKM0; BARX;
    }
    // ---- t = j+2: consume A-set, read tile j+3 -> B-set (buf3) ----
    {
      const int t = j + 2;
      if (t + 1 < NT) { RDT(aB, bB, 49152); }
      if (t + 3 < NT) STG(t + 3);
      MQ32(aA, bA);
      if (t + 3 < NT) { VM4; } else { VM0; }
      LGKM0; BARX;
    }
    // ---- t = j+3: consume B-set, read tile j+4 -> A-set (buf0) ----
    {
      const int t = j + 3;
      if (t + 1 < NT) { RDT(aA, bA, 0); }
      if (t + 3 < NT) STG(t + 3);
      MQ32(aB, bB);
      if (t + 3 < NT) { VM4; } else { VM0; }
      LGKM0; BARX;
    }
  }
  // loop exits: vmcnt==0, lgkm drained, all waves barrier-aligned.

  // epilogue
  const int cn = lane & 15;
  const int rr = (lane >> 4) * 4;
  const int row0 = by * 256 + wr * 128;
  const int col0 = bx * 256 + wc * 64;

  if (MODE == 0) {
    bf16_t* C = (bf16_t*)Cv;
#pragma unroll
    for (int m = 0; m < 8; ++m) {
      const int row = row0 + m * 16 + rr;
#pragma unroll
      for (int n = 0; n < 4; ++n) {
        const int col = col0 + n * 16 + cn;
        float bias = extra[col];
#pragma unroll
        for (int j = 0; j < 4; ++j)
          C[(long)(row + j) * N + col] = (bf16_t)(acc[m][n][j] + bias);
      }
    }
  } else if (MODE == 1) {
    bf16_t* C = (bf16_t*)Cv + (long)bz * sC;
    float* lds_f = (float*)lds;  // [wc][256 block-rows] wave-exclusive slots
#pragma unroll
    for (int m = 0; m < 8; ++m) {
      const int row = row0 + m * 16 + rr;
      float sm0 = 0.f, sm1 = 0.f, sm2 = 0.f, sm3 = 0.f;
#pragma unroll
      for (int n = 0; n < 4; ++n) {
        const int col = col0 + n * 16 + cn;
        float mk = extra[(long)bz * sE + col];
        float e0 = __expf(acc[m][n][0] * 0.03125f + mk);
        float e1 = __expf(acc[m][n][1] * 0.03125f + mk);
        float e2 = __expf(acc[m][n][2] * 0.03125f + mk);
        float e3 = __expf(acc[m][n][3] * 0.03125f + mk);
        C[(long)(row + 0) * N + col] = (bf16_t)e0;
        C[(long)(row + 1) * N + col] = (bf16_t)e1;
        C[(long)(row + 2) * N + col] = (bf16_t)e2;
        C[(long)(row + 3) * N + col] = (bf16_t)e3;
        sm0 += e0; sm1 += e1; sm2 += e2; sm3 += e3;
      }
      // column-reduce over the 16 lanes of this k-group (masks stay in-group)
#pragma unroll
      for (int w = 1; w < 16; w <<= 1) {
        sm0 += __shfl_xor(sm0, w, 64);
        sm1 += __shfl_xor(sm1, w, 64);
        sm2 += __shfl_xor(sm2, w, 64);
        sm3 += __shfl_xor(sm3, w, 64);
      }
      if (cn == 0) {
        const int br = wr * 128 + m * 16 + (lane >> 4) * 4;
        lds_f[wc * 256 + br + 0] = sm0;
        lds_f[wc * 256 + br + 1] = sm1;
        lds_f[wc * 256 + br + 2] = sm2;
        lds_f[wc * 256 + br + 3] = sm3;
      }
    }
    __syncthreads();
    if (tid < 256) {
      float s4 = lds_f[tid] + lds_f[256 + tid] + lds_f[512 + tid] +
                 lds_f[768 + tid];
      extra2[((long)bz * 8 + bx) * 2048 + by * 256 + tid] = s4;
    }
  } else {
    float* C = (float*)Cv + (long)bz * sC;
    const float* rinv = extra + (long)bz * 2048;
#pragma unroll
    for (int m = 0; m < 8; ++m) {
      const int row = row0 + m * 16 + rr;
      float i0 = rinv[row + 0], i1 = rinv[row + 1];
      float i2 = rinv[row + 2], i3 = rinv[row + 3];
#pragma unroll
      for (int n = 0; n < 4; ++n) {
        const int col = col0 + n * 16 + cn;
        C[(long)(row + 0) * N + col] = acc[m][n][0] * i0;
        C[(long)(row + 1) * N + col] = acc[m][n][1] * i1;
        C[(long)(row + 2) * N + col] = acc[m][n][2] * i2;
        C[(long)(row + 3) * N + col] = acc[m][n][3] * i3;
      }
    }
  }
}

extern "C" void kernel_launch(void* const* d_in, const int* in_sizes, int n_in,
                              void* d_out, int out_size, void* d_ws, size_t ws_size,
                              hipStream_t stream) {
  const float* x    = (const float*)d_in[0];
  const float* mask = (const float*)d_in[1];
  const float* keys = (const float*)d_in[2];
  const float* vals = (const float*)d_in[3];
  const float* Wq   = (const float*)d_in[4];
  const float* bq   = (const float*)d_in[5];
  float* out = (float*)d_out;

  char* ws = (char*)d_ws;
  bf16_t* kbf    = (bf16_t*)(ws);
  bf16_t* vt     = (bf16_t*)(ws + 33554432);
  bf16_t* qbf    = (bf16_t*)(ws + 67108864);
  bf16_t* logits = (bf16_t*)(ws + 100663296);  // holds p_unnorm = exp(logit)
  bf16_t* xbf    = logits;  // reused: x_bf dead before logits are written
  bf16_t* wqbf   = (bf16_t*)(ws + 167772160);
  // wqbf region (2 MB) is dead after Q-proj; reuse for rowsum buffers:
  float* pbuf = (float*)(ws + 167772160);            // [8][8][2048] partials
  float* rinv = (float*)(ws + 167772160 + 524288);   // [8][2048] 1/rowsum

  // 1. converts
  cvt_bf16_kernel<<<2048, 256, 0, stream>>>(x, xbf, (B_ * LQ_ * DM_) / 8);
  cvt_bf16_kernel<<<2048, 256, 0, stream>>>(keys, kbf, (B_ * LK_ * DM_) / 8);
  cvt_bf16_kernel<<<256, 256, 0, stream>>>(Wq, wqbf, (DM_ * DM_) / 8);
  transpose_v<<<dim3(LK_ / 64, DM_ / 64, B_), 256, 0, stream>>>(vals, vt);

  // 2. Q = x @ Wq^T + bq   (M=16384, N=1024, K=1024) grid 4x64 = 256
  gemm_bt<0><<<256, 512, 0, stream>>>(
      xbf, wqbf, qbf, bq, nullptr, DM_, DM_, 0, 0, 0, 0, 2, 6);

  // 3. p_unnorm = exp(Q @ K^T / 32 + mask), + rowsum partials
  gemm_bt<1><<<512, 512, 0, stream>>>(
      qbf, kbf, logits, mask, pbuf, LK_, DM_,
      (long)LQ_ * DM_, (long)LK_ * DM_, (long)LQ_ * LK_, LK_, 3, 3);

  // 4. rinv = 1 / rowsum
  rowsum_inv_kernel<<<64, 256, 0, stream>>>(pbuf, rinv);

  // 5. out = (P @ Vt^T) * rinv[row]  (per batch M=2048, N=1024, K=2048)
  gemm_bt<2><<<256, 512, 0, stream>>>(
      logits, vt, out, rinv, nullptr, DM_, LK_,
      (long)LQ_ * LK_, (long)DM_ * LK_, (long)LQ_ * DM_, 0, 2, 3);
}

// Round 12
// 250.719 us; speedup vs baseline: 1.0152x; 1.0152x over previous
//
#include <hip/hip_runtime.h>
#include <hip/hip_bf16.h>

typedef __bf16 bf16_t;
typedef __bf16 bf16x8 __attribute__((ext_vector_type(8)));
typedef float f32x4 __attribute__((ext_vector_type(4)));

#define B_ 8
#define LQ_ 2048
#define LK_ 2048
#define DM_ 1024

__device__ __forceinline__ void gload16(const void* g, void* l) {
  __builtin_amdgcn_global_load_lds(
      (const __attribute__((address_space(1))) void*)g,
      (__attribute__((address_space(3))) void*)l, 16, 0, 0);
}

// ---------------- f32 -> bf16 convert (vectorized) ----------------
__global__ __launch_bounds__(256) void cvt_bf16_kernel(
    const float* __restrict__ in, bf16_t* __restrict__ out, int n8) {
  int stride = gridDim.x * blockDim.x;
  for (int i = blockIdx.x * blockDim.x + threadIdx.x; i < n8; i += stride) {
    const float4* p = reinterpret_cast<const float4*>(in) + (size_t)i * 2;
    float4 a = p[0], b = p[1];
    bf16x8 o;
    o[0] = (bf16_t)a.x; o[1] = (bf16_t)a.y; o[2] = (bf16_t)a.z; o[3] = (bf16_t)a.w;
    o[4] = (bf16_t)b.x; o[5] = (bf16_t)b.y; o[6] = (bf16_t)b.z; o[7] = (bf16_t)b.w;
    *reinterpret_cast<bf16x8*>(out + (size_t)i * 8) = o;
  }
}

// ---------------- V [B][LK][DM] f32 -> Vt [B][DM][LK] bf16 ----------------
__global__ __launch_bounds__(256) void transpose_v(
    const float* __restrict__ V, bf16_t* __restrict__ Vt) {
  __shared__ bf16_t tile[64][65];
  int b = blockIdx.z;
  int k0 = blockIdx.x * 64;
  int d0 = blockIdx.y * 64;
  int r = threadIdx.x >> 6;
  int c = threadIdx.x & 63;
  const float* src = V + ((size_t)b * LK_ + k0) * DM_ + d0;
#pragma unroll
  for (int i = 0; i < 64; i += 4)
    tile[r + i][c] = (bf16_t)src[(size_t)(r + i) * DM_ + c];
  __syncthreads();
  bf16_t* dst = Vt + ((size_t)b * DM_ + d0) * LK_ + k0;
#pragma unroll
  for (int i = 0; i < 64; i += 4)
    dst[(size_t)(r + i) * LK_ + c] = tile[c][r + i];
}

// ---------------- rowsum partials -> inverse rowsums ----------------
__global__ __launch_bounds__(256) void rowsum_inv_kernel(
    const float* __restrict__ pbuf, float* __restrict__ rinv) {
  int R = blockIdx.x * 256 + threadIdx.x;  // 0..16383
  int b = R >> 11, row = R & 2047;
  float s = 0.f;
#pragma unroll
  for (int cb = 0; cb < 8; ++cb)
    s += pbuf[((long)b * 8 + cb) * 2048 + row];
  rinv[R] = 1.0f / s;
}

// ------------- 256x256 READ-AHEAD GEMM (swizzled), C = A * B^T -------------
// r11 rerun with the bank-conflict fix. BK=32 rows are 64B: linear b128
// fragment reads were 8-way conflicted (r11: 6.3M counts). Swizzle
// phys_slot = slot ^ ((row>>1)&3) (involution, both sides: pre-swizzled
// global source + swizzled read slot) -> 2 lanes/16B-granule = free.
// Pipeline (r11): interval t = {issue ds_reads tile t+1 into other reg set;
// stage tile t+3; MFMA tile t from resident regs; vmcnt(4); lgkm0; barrier}.
// LDS read queue drains under MFMA; LGKM0-before-barrier is WAR-load-bearing
// (cross-wave: reads complete before any wave's later overwrite staging).
// BK=32, 4 LDS buffers (128KB), 8 waves 2Mx4N, wave tile 128x64.
// MODE 0: C bf16, C += bias[col]                    (Q projection)
// MODE 1: C bf16, C = exp(C/32 + mask[b][col]); + rowsum partials->extra2
// MODE 2: C f32,  C = acc * rinv[b][row]            (extra = rinv)
#define BARX __builtin_amdgcn_s_barrier()
#define PRIO1 __builtin_amdgcn_s_setprio(1)
#define PRIO0 __builtin_amdgcn_s_setprio(0)
#define VM4 asm volatile("s_waitcnt vmcnt(4)" ::: "memory")
#define VM0 asm volatile("s_waitcnt vmcnt(0)" ::: "memory")
#define LGKM0 asm volatile("s_waitcnt lgkmcnt(0)" ::: "memory")

#define RDT(AS, BS, BUFE)                                                     \
  _Pragma("unroll") for (int m = 0; m < 8; ++m)                               \
      AS[m] = *(const bf16x8*)(pa + (BUFE) + m * 512);                        \
  _Pragma("unroll") for (int n = 0; n < 4; ++n)                               \
      BS[n] = *(const bf16x8*)(pb + (BUFE) + n * 512);

#define MQ32(AS, BS)                                                          \
  PRIO1;                                                                      \
  _Pragma("unroll") for (int m = 0; m < 8; ++m)                               \
  _Pragma("unroll") for (int n = 0; n < 4; ++n)                               \
      acc[m][n] = __builtin_amdgcn_mfma_f32_16x16x32_bf16(                    \
          AS[m], BS[n], acc[m][n], 0, 0, 0);                                  \
  PRIO0;

template <int MODE>
__global__ __launch_bounds__(512, 1) void gemm_bt(
    const bf16_t* __restrict__ A, const bf16_t* __restrict__ Bm,
    void* __restrict__ Cv, const float* __restrict__ extra,
    float* __restrict__ extra2,
    int N, int K, long sA, long sB, long sC, long sE, int gxs, int gys) {
  __shared__ bf16_t lds[65536];  // 4 bufs x (A 8192 + B 8192) elems = 128 KiB

  const int tid = threadIdx.x;
  const int lane = tid & 63;
  const int wave = tid >> 6;

  // XCD-aware bijective block swizzle (gridDim.x % 8 == 0 for all our grids)
  const int nwg = gridDim.x;
  const int lin = blockIdx.x;
  const int cpx = nwg >> 3;
  const int swz = (lin & 7) * cpx + (lin >> 3);
  const int gx = 1 << gxs;
  const int bx = swz & (gx - 1);
  const int rem = swz >> gxs;
  const int by = rem & ((1 << gys) - 1);
  const int bz = rem >> gys;

  const bf16_t* Ab = A + (long)bz * sA + (long)(by * 256) * K;
  const bf16_t* Bb = Bm + (long)bz * sB + (long)(bx * 256) * K;

  // staging: thread tid covers chunk (row = tid>>2, phys_slot = tid&3) and
  // the +128-row twin. Source col pre-swizzled: logical slot = phys ^ q(row).
  const int rA = tid >> 2;                                  // 0..127
  const int cA = ((tid & 3) ^ ((rA >> 1) & 3)) * 8;         // pre-swizzled

  auto STG = [&](int t) {
    const int bufe = (t & 3) * 16384;
    const bf16_t* gA = Ab + (long)rA * K + t * 32 + cA;
    const bf16_t* gB = Bb + (long)rA * K + t * 32 + cA;
    bf16_t* l = lds + bufe + tid * 8;
    gload16(gA, l);
    gload16(gA + (long)128 * K, l + 4096);   // row+128: q unchanged (64&3=0)
    gload16(gB, l + 8192);
    gload16(gB + (long)128 * K, l + 12288);
  };

  // fragment read geometry: row fr, logical k-chunk g -> phys slot g ^ q(fr)
  const int wr = wave >> 2;   // 0..1
  const int wc = wave & 3;    // 0..3
  const int fr = lane & 15;
  const int sp8 = (((lane >> 4) ^ ((fr >> 1) & 3))) * 8;   // swizzled slot
  const bf16_t* pa = lds + (wr * 128 + fr) * 32 + sp8;         // + m*512
  const bf16_t* pb = lds + 8192 + (wc * 64 + fr) * 32 + sp8;   // + n*512

  f32x4 acc[8][4] = {};
  bf16x8 aA[8], bA[4], aB[8], bB[4];

  const int NT = K >> 5;  // K-tiles (BK=32); multiple of 4 here (32 or 64)

  // prologue: stage t0,t1,t2; drain t0,t1 (keep t2 in flight); read tile0.
  STG(0); STG(1); STG(2);
  VM4; BARX;
  RDT(aA, bA, 0);

  for (int j = 0; j < NT; j += 4) {
    // ---- t = j: consume A-set, read tile j+1 -> B-set (buf1) ----
    {
      const int t = j;
      if (t + 1 < NT) { RDT(aB, bB, 16384); }
      if (t + 3 < NT) STG(t + 3);
      MQ32(aA, bA);
      if (t + 3 < NT) { VM4; } else { VM0; }
      LGKM0; BARX;
    }
    // ---- t = j+1: consume B-set, read tile j+2 -> A-set (buf2) ----
    {
      const int t = j + 1;
      if (t + 1 < NT) { RDT(aA, bA, 32768); }
      if (t + 3 < NT) STG(t + 3);
      MQ32(aB, bB);
      if (t + 3 < NT) { VM4; } else { VM0; }
      LGKM0; BARX;
    }
    // ---- t = j+2: consume A-set, read tile j+3 -> B-set (buf3) ----
    {
      const int t = j + 2;
      if (t + 1 < NT) { RDT(aB, bB, 49152); }
      if (t + 3 < NT) STG(t + 3);
      MQ32(aA, bA);
      if (t + 3 < NT) { VM4; } else { VM0; }
      LGKM0; BARX;
    }
    // ---- t = j+3: consume B-set, read tile j+4 -> A-set (buf0) ----
    {
      const int t = j + 3;
      if (t + 1 < NT) { RDT(aA, bA, 0); }
      if (t + 3 < NT) STG(t + 3);
      MQ32(aB, bB);
      if (t + 3 < NT) { VM4; } else { VM0; }
      LGKM0; BARX;
    }
  }
  // loop exits: vmcnt==0, lgkm drained, all waves barrier-aligned.

  // epilogue
  const int cn = lane & 15;
  const int rr = (lane >> 4) * 4;
  const int row0 = by * 256 + wr * 128;
  const int col0 = bx * 256 + wc * 64;

  if (MODE == 0) {
    bf16_t* C = (bf16_t*)Cv;
#pragma unroll
    for (int m = 0; m < 8; ++m) {
      const int row = row0 + m * 16 + rr;
#pragma unroll
      for (int n = 0; n < 4; ++n) {
        const int col = col0 + n * 16 + cn;
        float bias = extra[col];
#pragma unroll
        for (int j = 0; j < 4; ++j)
          C[(long)(row + j) * N + col] = (bf16_t)(acc[m][n][j] + bias);
      }
    }
  } else if (MODE == 1) {
    bf16_t* C = (bf16_t*)Cv + (long)bz * sC;
    float* lds_f = (float*)lds;  // [wc][256 block-rows] wave-exclusive slots
#pragma unroll
    for (int m = 0; m < 8; ++m) {
      const int row = row0 + m * 16 + rr;
      float sm0 = 0.f, sm1 = 0.f, sm2 = 0.f, sm3 = 0.f;
#pragma unroll
      for (int n = 0; n < 4; ++n) {
        const int col = col0 + n * 16 + cn;
        float mk = extra[(long)bz * sE + col];
        float e0 = __expf(acc[m][n][0] * 0.03125f + mk);
        float e1 = __expf(acc[m][n][1] * 0.03125f + mk);
        float e2 = __expf(acc[m][n][2] * 0.03125f + mk);
        float e3 = __expf(acc[m][n][3] * 0.03125f + mk);
        C[(long)(row + 0) * N + col] = (bf16_t)e0;
        C[(long)(row + 1) * N + col] = (bf16_t)e1;
        C[(long)(row + 2) * N + col] = (bf16_t)e2;
        C[(long)(row + 3) * N + col] = (bf16_t)e3;
        sm0 += e0; sm1 += e1; sm2 += e2; sm3 += e3;
      }
      // column-reduce over the 16 lanes of this k-group (masks stay in-group)
#pragma unroll
      for (int w = 1; w < 16; w <<= 1) {
        sm0 += __shfl_xor(sm0, w, 64);
        sm1 += __shfl_xor(sm1, w, 64);
        sm2 += __shfl_xor(sm2, w, 64);
        sm3 += __shfl_xor(sm3, w, 64);
      }
      if (cn == 0) {
        const int br = wr * 128 + m * 16 + (lane >> 4) * 4;
        lds_f[wc * 256 + br + 0] = sm0;
        lds_f[wc * 256 + br + 1] = sm1;
        lds_f[wc * 256 + br + 2] = sm2;
        lds_f[wc * 256 + br + 3] = sm3;
      }
    }
    __syncthreads();
    if (tid < 256) {
      float s4 = lds_f[tid] + lds_f[256 + tid] + lds_f[512 + tid] +
                 lds_f[768 + tid];
      extra2[((long)bz * 8 + bx) * 2048 + by * 256 + tid] = s4;
    }
  } else {
    float* C = (float*)Cv + (long)bz * sC;
    const float* rinv = extra + (long)bz * 2048;
#pragma unroll
    for (int m = 0; m < 8; ++m) {
      const int row = row0 + m * 16 + rr;
      float i0 = rinv[row + 0], i1 = rinv[row + 1];
      float i2 = rinv[row + 2], i3 = rinv[row + 3];
#pragma unroll
      for (int n = 0; n < 4; ++n) {
        const int col = col0 + n * 16 + cn;
        C[(long)(row + 0) * N + col] = acc[m][n][0] * i0;
        C[(long)(row + 1) * N + col] = acc[m][n][1] * i1;
        C[(long)(row + 2) * N + col] = acc[m][n][2] * i2;
        C[(long)(row + 3) * N + col] = acc[m][n][3] * i3;
      }
    }
  }
}

extern "C" void kernel_launch(void* const* d_in, const int* in_sizes, int n_in,
                              void* d_out, int out_size, void* d_ws, size_t ws_size,
                              hipStream_t stream) {
  const float* x    = (const float*)d_in[0];
  const float* mask = (const float*)d_in[1];
  const float* keys = (const float*)d_in[2];
  const float* vals = (const float*)d_in[3];
  const float* Wq   = (const float*)d_in[4];
  const float* bq   = (const float*)d_in[5];
  float* out = (float*)d_out;

  char* ws = (char*)d_ws;
  bf16_t* kbf    = (bf16_t*)(ws);
  bf16_t* vt     = (bf16_t*)(ws + 33554432);
  bf16_t* qbf    = (bf16_t*)(ws + 67108864);
  bf16_t* logits = (bf16_t*)(ws + 100663296);  // holds p_unnorm = exp(logit)
  bf16_t* xbf    = logits;  // reused: x_bf dead before logits are written
  bf16_t* wqbf   = (bf16_t*)(ws + 167772160);
  // wqbf region (2 MB) is dead after Q-proj; reuse for rowsum buffers:
  float* pbuf = (float*)(ws + 167772160);            // [8][8][2048] partials
  float* rinv = (float*)(ws + 167772160 + 524288);   // [8][2048] 1/rowsum

  // 1. converts
  cvt_bf16_kernel<<<2048, 256, 0, stream>>>(x, xbf, (B_ * LQ_ * DM_) / 8);
  cvt_bf16_kernel<<<2048, 256, 0, stream>>>(keys, kbf, (B_ * LK_ * DM_) / 8);
  cvt_bf16_kernel<<<256, 256, 0, stream>>>(Wq, wqbf, (DM_ * DM_) / 8);
  transpose_v<<<dim3(LK_ / 64, DM_ / 64, B_), 256, 0, stream>>>(vals, vt);

  // 2. Q = x @ Wq^T + bq   (M=16384, N=1024, K=1024) grid 4x64 = 256
  gemm_bt<0><<<256, 512, 0, stream>>>(
      xbf, wqbf, qbf, bq, nullptr, DM_, DM_, 0, 0, 0, 0, 2, 6);

  // 3. p_unnorm = exp(Q @ K^T / 32 + mask), + rowsum partials
  gemm_bt<1><<<512, 512, 0, stream>>>(
      qbf, kbf, logits, mask, pbuf, LK_, DM_,
      (long)LQ_ * DM_, (long)LK_ * DM_, (long)LQ_ * LK_, LK_, 3, 3);

  // 4. rinv = 1 / rowsum
  rowsum_inv_kernel<<<64, 256, 0, stream>>>(pbuf, rinv);

  // 5. out = (P @ Vt^T) * rinv[row]  (per batch M=2048, N=1024, K=2048)
  gemm_bt<2><<<256, 512, 0, stream>>>(
      logits, vt, out, rinv, nullptr, DM_, LK_,
      (long)LQ_ * LK_, (long)DM_ * LK_, (long)LQ_ * DM_, 0, 2, 3);
}

// Round 13
// 234.182 us; speedup vs baseline: 1.0868x; 1.0706x over previous
//
#include <hip/hip_runtime.h>
#include <hip/hip_bf16.h>

typedef __bf16 bf16_t;
typedef __bf16 bf16x8 __attribute__((ext_vector_type(8)));
typedef float f32x4 __attribute__((ext_vector_type(4)));

#define B_ 8
#define LQ_ 2048
#define LK_ 2048
#define DM_ 1024

__device__ __forceinline__ void gload16(const void* g, void* l) {
  __builtin_amdgcn_global_load_lds(
      (const __attribute__((address_space(1))) void*)g,
      (__attribute__((address_space(3))) void*)l, 16, 0, 0);
}

// ------------- fused prep: x/keys/Wq f32->bf16 + V transpose -------------
// block ranges: [0,1024) x-cvt | [1024,2048) keys-cvt | [2048,2176) Wq-cvt |
// [2176,6272) V 64x64 transpose tiles. All HBM-bound; fused to kill launch
// gaps between 4 small kernels.
__global__ __launch_bounds__(256) void prep_kernel(
    const float* __restrict__ x, const float* __restrict__ keys,
    const float* __restrict__ Wq, const float* __restrict__ vals,
    bf16_t* __restrict__ xbf, bf16_t* __restrict__ kbf,
    bf16_t* __restrict__ wqbf, bf16_t* __restrict__ vt) {
  const int bid = blockIdx.x;
  if (bid < 2176) {
    const float* in;
    bf16_t* out;
    int n8, i0, nb;
    if (bid < 1024) {
      in = x; out = xbf; n8 = (B_ * LQ_ * DM_) / 8; i0 = bid; nb = 1024;
    } else if (bid < 2048) {
      in = keys; out = kbf; n8 = (B_ * LK_ * DM_) / 8; i0 = bid - 1024; nb = 1024;
    } else {
      in = Wq; out = wqbf; n8 = (DM_ * DM_) / 8; i0 = bid - 2048; nb = 128;
    }
    int stride = nb * 256;
    for (int i = i0 * 256 + threadIdx.x; i < n8; i += stride) {
      const float4* p = reinterpret_cast<const float4*>(in) + (size_t)i * 2;
      float4 a = p[0], b = p[1];
      bf16x8 o;
      o[0] = (bf16_t)a.x; o[1] = (bf16_t)a.y; o[2] = (bf16_t)a.z; o[3] = (bf16_t)a.w;
      o[4] = (bf16_t)b.x; o[5] = (bf16_t)b.y; o[6] = (bf16_t)b.z; o[7] = (bf16_t)b.w;
      *reinterpret_cast<bf16x8*>(out + (size_t)i * 8) = o;
    }
  } else {
    __shared__ bf16_t tile[64][65];
    const int t = bid - 2176;            // 0..4095
    const int k0 = (t & 31) * 64;
    const int d0 = ((t >> 5) & 15) * 64;
    const int b = t >> 9;
    const int r = threadIdx.x >> 6;
    const int c = threadIdx.x & 63;
    const float* src = vals + ((size_t)b * LK_ + k0) * DM_ + d0;
#pragma unroll
    for (int i = 0; i < 64; i += 4)
      tile[r + i][c] = (bf16_t)src[(size_t)(r + i) * DM_ + c];
    __syncthreads();
    bf16_t* dst = vt + ((size_t)b * DM_ + d0) * LK_ + k0;
#pragma unroll
    for (int i = 0; i < 64; i += 4)
      dst[(size_t)(r + i) * LK_ + c] = tile[c][r + i];
  }
}

// ---------------- rowsum partials -> inverse rowsums ----------------
__global__ __launch_bounds__(256) void rowsum_inv_kernel(
    const float* __restrict__ pbuf, float* __restrict__ rinv) {
  int R = blockIdx.x * 256 + threadIdx.x;  // 0..16383
  int b = R >> 11, row = R & 2047;
  float s = 0.f;
#pragma unroll
  for (int cb = 0; cb < 8; ++cb)
    s += pbuf[((long)b * 8 + cb) * 2048 + row];
  rinv[R] = 1.0f / s;
}

// ---------------- 256x256 8-phase GEMM, C = A * B^T (round-8 exact) -------
// Race-free skeleton: every vmcnt drain sits BEFORE the end-of-phase
// barrier; staged regions are read only in phases after that drain+barrier.
// BK=64, 2 K-tiles/iter, 8 waves (2Mx4N), wave tile 128x64, 128 KiB LDS.
// K-slot swizzle (involution): phys_slot = slot ^ ((row>>1)&7), 8x16B slots.
// MODE 0: C bf16, C += bias[col]                    (Q projection)
// MODE 1: C bf16, C = exp(C/32 + mask[b][col]); + rowsum partials->extra2
// MODE 2: C f32,  C = acc * rinv[b][row]            (extra = rinv)
#define BARX __builtin_amdgcn_s_barrier()
#define PRIO1 __builtin_amdgcn_s_setprio(1)
#define PRIO0 __builtin_amdgcn_s_setprio(0)

#define RD_A(QM, DOFF)                                                        \
  _Pragma("unroll") for (int m = 0; m < 4; ++m) {                             \
    aF[m][0] = *(const bf16x8*)(pa0 + (QM)*8192 + (DOFF) + m * 2048);         \
    aF[m][1] = *(const bf16x8*)(pa1 + (QM)*8192 + (DOFF) + m * 2048);         \
  }
#define RD_B2(NB, DOFF)                                                       \
  _Pragma("unroll") for (int n = 0; n < 2; ++n) {                             \
    bF[(NB) + n][0] = *(const bf16x8*)(pb0 + (DOFF) + ((NB) + n) * 2048);     \
    bF[(NB) + n][1] = *(const bf16x8*)(pb1 + (DOFF) + ((NB) + n) * 2048);     \
  }
// kk=0 for all (m,n) first, then kk=1: dependent accumulate pairs are 8
// ops apart instead of back-to-back.
#define MFMA_QUAD(MB, NB)                                                     \
  _Pragma("unroll") for (int m = 0; m < 4; ++m)                               \
  _Pragma("unroll") for (int n = 0; n < 2; ++n)                               \
    acc[(MB) + m][(NB) + n] = __builtin_amdgcn_mfma_f32_16x16x32_bf16(        \
        aF[m][0], bF[(NB) + n][0], acc[(MB) + m][(NB) + n], 0, 0, 0);         \
  _Pragma("unroll") for (int m = 0; m < 4; ++m)                               \
  _Pragma("unroll") for (int n = 0; n < 2; ++n)                               \
    acc[(MB) + m][(NB) + n] = __builtin_amdgcn_mfma_f32_16x16x32_bf16(        \
        aF[m][1], bF[(NB) + n][1], acc[(MB) + m][(NB) + n], 0, 0, 0);

template <int MODE>
__global__ __launch_bounds__(512, 2) void gemm_bt(
    const bf16_t* __restrict__ A, const bf16_t* __restrict__ Bm,
    void* __restrict__ Cv, const float* __restrict__ extra,
    float* __restrict__ extra2,
    int N, int K, long sA, long sB, long sC, long sE, int gxs, int gys) {
  __shared__ bf16_t lds[65536];  // A: d0 [0,32KB) d1 [32,64KB); B: [64,128KB)

  const int tid = threadIdx.x;
  const int lane = tid & 63;
  const int wave = tid >> 6;

  // XCD-aware bijective block swizzle (gridDim.x % 8 == 0 for all our grids)
  const int nwg = gridDim.x;
  const int lin = blockIdx.x;
  const int cpx = nwg >> 3;
  const int swz = (lin & 7) * cpx + (lin >> 3);
  const int gx = 1 << gxs;
  const int bx = swz & (gx - 1);
  const int rem = swz >> gxs;
  const int by = rem & ((1 << gys) - 1);
  const int bz = rem >> gys;

  const bf16_t* Ab = A + (long)bz * sA + (long)(by * 256) * K;
  const bf16_t* Bb = Bm + (long)bz * sB + (long)(bx * 256) * K;

  // staging geometry: chunk c = tid; row-in-half = c>>3, phys slot c&7
  const int r0 = tid >> 3;                              // 0..63
  const int scol = ((tid & 7) ^ ((r0 >> 1) & 7)) * 8;   // pre-swizzled col

  auto STG = [&](const bf16_t* Mb, int d, int mat, int h, int t) {
    const bf16_t* g = Mb + (long)(h * 128 + r0) * K + t * 64 + scol;
    bf16_t* l = lds + mat * 32768 + d * 16384 + h * 8192 + wave * 512;
    gload16(g, l);
    gload16(g + (long)64 * K, l + 4096);
  };

  // fragment read geometry
  const int wr = wave >> 2;   // 0..1
  const int wc = wave & 3;    // 0..3
  const int fr = lane & 15;
  const int g = lane >> 4;
  const int q5 = (fr >> 1) & 7;
  const int sb0 = (g ^ q5) * 16;         // kk=0 slot bytes (phys)
  const int sb1 = ((4 + g) ^ q5) * 16;   // kk=1
  const char* ldsc = (const char*)lds;
  const char* pa0 = ldsc + (wr * 128 + fr) * 128 + sb0;
  const char* pa1 = ldsc + (wr * 128 + fr) * 128 + sb1;
  const char* pb0 = ldsc + 65536 + (wc * 64 + fr) * 128 + sb0;
  const char* pb1 = ldsc + 65536 + (wc * 64 + fr) * 128 + sb1;

  f32x4 acc[8][4] = {};
  bf16x8 aF[4][2], bF[4][2];

  const int NT2 = K >> 7;  // iterations, 2 K-tiles (BK=64) each

  // prologue: t0 full (8 loads) + t1 B h0,h1 (4 loads)
  STG(Ab, 0, 0, 0, 0); STG(Ab, 0, 0, 1, 0);
  STG(Bb, 0, 1, 0, 0); STG(Bb, 0, 1, 1, 0);
  STG(Bb, 1, 1, 0, 1); STG(Bb, 1, 1, 1, 1);
  asm volatile("s_waitcnt vmcnt(4)" ::: "memory");  // t0 complete, t1.B in flight
  BARX;

  for (int j = 0; j < NT2; ++j) {
    const bool nl = (j + 1 < NT2);
    const int t1 = 2 * j + 1, t2 = 2 * j + 2, t3 = 2 * j + 3;
    // ---- P1: quadrant (qm0,qn01) of dbuf0 ----
    RD_A(0, 0); RD_B2(0, 0);
    STG(Ab, 1, 0, 0, t1);
    BARX; PRIO1; MFMA_QUAD(0, 0); PRIO0; BARX;
    // ---- P2: (qm0,qn23) ----
    RD_B2(2, 0);
    STG(Ab, 1, 0, 1, t1);
    BARX; PRIO1; MFMA_QUAD(0, 2); PRIO0; BARX;
    // ---- P3: (qm1,qn23) ----
    RD_A(1, 0);
    if (nl) STG(Bb, 0, 1, 0, t2);
    BARX; PRIO1; MFMA_QUAD(4, 2); PRIO0; BARX;
    // ---- P4: (qm1,qn01); dbuf1 must be complete after this phase ----
    if (nl) STG(Bb, 0, 1, 1, t2);
    BARX; PRIO1; MFMA_QUAD(4, 0); PRIO0;
    if (nl) { asm volatile("s_waitcnt vmcnt(4)" ::: "memory"); }
    else    { asm volatile("s_waitcnt vmcnt(0)" ::: "memory"); }
    BARX;
    // ---- P5: (qm0,qn01) of dbuf1 ----
    RD_A(0, 32768); RD_B2(0, 32768);
    if (nl) STG(Ab, 0, 0, 0, t2);
    BARX; PRIO1; MFMA_QUAD(0, 0); PRIO0; BARX;
    // ---- P6: (qm0,qn23) ----
    RD_B2(2, 32768);
    if (nl) STG(Ab, 0, 0, 1, t2);
    BARX; PRIO1; MFMA_QUAD(0, 2); PRIO0; BARX;
    // ---- P7: (qm1,qn23) ----
    RD_A(1, 32768);
    if (nl) STG(Bb, 1, 1, 0, t3);
    BARX; PRIO1; MFMA_QUAD(4, 2); PRIO0; BARX;
    // ---- P8: (qm1,qn01); dbuf0 must be complete after this phase ----
    if (nl) STG(Bb, 1, 1, 1, t3);
    BARX; PRIO1; MFMA_QUAD(4, 0); PRIO0;
    if (nl) { asm volatile("s_waitcnt vmcnt(4)" ::: "memory"); }
    BARX;
  }
  // loop exits with vmcnt==0 and all LDS reads complete -> LDS reusable.

  // epilogue
  const int cn = lane & 15;
  const int rr = (lane >> 4) * 4;
  const int row0 = by * 256 + wr * 128;
  const int col0 = bx * 256 + wc * 64;

  if (MODE == 0) {
    bf16_t* C = (bf16_t*)Cv;
#pragma unroll
    for (int m = 0; m < 8; ++m) {
      const int row = row0 + m * 16 + rr;
#pragma unroll
      for (int n = 0; n < 4; ++n) {
        const int col = col0 + n * 16 + cn;
        float bias = extra[col];
#pragma unroll
        for (int j = 0; j < 4; ++j)
          C[(long)(row + j) * N + col] = (bf16_t)(acc[m][n][j] + bias);
      }
    }
  } else if (MODE == 1) {
    bf16_t* C = (bf16_t*)Cv + (long)bz * sC;
    float* lds_f = (float*)lds;  // [wc][256 block-rows] wave-exclusive slots
#pragma unroll
    for (int m = 0; m < 8; ++m) {
      const int row = row0 + m * 16 + rr;
      float sm0 = 0.f, sm1 = 0.f, sm2 = 0.f, sm3 = 0.f;
#pragma unroll
      for (int n = 0; n < 4; ++n) {
        const int col = col0 + n * 16 + cn;
        float mk = extra[(long)bz * sE + col];
        float e0 = __expf(acc[m][n][0] * 0.03125f + mk);
        float e1 = __expf(acc[m][n][1] * 0.03125f + mk);
        float e2 = __expf(acc[m][n][2] * 0.03125f + mk);
        float e3 = __expf(acc[m][n][3] * 0.03125f + mk);
        C[(long)(row + 0) * N + col] = (bf16_t)e0;
        C[(long)(row + 1) * N + col] = (bf16_t)e1;
        C[(long)(row + 2) * N + col] = (bf16_t)e2;
        C[(long)(row + 3) * N + col] = (bf16_t)e3;
        sm0 += e0; sm1 += e1; sm2 += e2; sm3 += e3;
      }
      // column-reduce over the 16 lanes of this k-group (masks stay in-group)
#pragma unroll
      for (int w = 1; w < 16; w <<= 1) {
        sm0 += __shfl_xor(sm0, w, 64);
        sm1 += __shfl_xor(sm1, w, 64);
        sm2 += __shfl_xor(sm2, w, 64);
        sm3 += __shfl_xor(sm3, w, 64);
      }
      if (cn == 0) {
        const int br = wr * 128 + m * 16 + (lane >> 4) * 4;
        lds_f[wc * 256 + br + 0] = sm0;
        lds_f[wc * 256 + br + 1] = sm1;
        lds_f[wc * 256 + br + 2] = sm2;
        lds_f[wc * 256 + br + 3] = sm3;
      }
    }
    __syncthreads();
    if (tid < 256) {
      float s4 = lds_f[tid] + lds_f[256 + tid] + lds_f[512 + tid] +
                 lds_f[768 + tid];
      extra2[((long)bz * 8 + bx) * 2048 + by * 256 + tid] = s4;
    }
  } else {
    float* C = (float*)Cv + (long)bz * sC;
    const float* rinv = extra + (long)bz * 2048;
#pragma unroll
    for (int m = 0; m < 8; ++m) {
      const int row = row0 + m * 16 + rr;
      float i0 = rinv[row + 0], i1 = rinv[row + 1];
      float i2 = rinv[row + 2], i3 = rinv[row + 3];
#pragma unroll
      for (int n = 0; n < 4; ++n) {
        const int col = col0 + n * 16 + cn;
        C[(long)(row + 0) * N + col] = acc[m][n][0] * i0;
        C[(long)(row + 1) * N + col] = acc[m][n][1] * i1;
        C[(long)(row + 2) * N + col] = acc[m][n][2] * i2;
        C[(long)(row + 3) * N + col] = acc[m][n][3] * i3;
      }
    }
  }
}

extern "C" void kernel_launch(void* const* d_in, const int* in_sizes, int n_in,
                              void* d_out, int out_size, void* d_ws, size_t ws_size,
                              hipStream_t stream) {
  const float* x    = (const float*)d_in[0];
  const float* mask = (const float*)d_in[1];
  const float* keys = (const float*)d_in[2];
  const float* vals = (const float*)d_in[3];
  const float* Wq   = (const float*)d_in[4];
  const float* bq   = (const float*)d_in[5];
  float* out = (float*)d_out;

  char* ws = (char*)d_ws;
  bf16_t* kbf    = (bf16_t*)(ws);
  bf16_t* vt     = (bf16_t*)(ws + 33554432);
  bf16_t* qbf    = (bf16_t*)(ws + 67108864);
  bf16_t* logits = (bf16_t*)(ws + 100663296);  // holds p_unnorm = exp(logit)
  bf16_t* xbf    = logits;  // reused: x_bf dead before logits are written
  bf16_t* wqbf   = (bf16_t*)(ws + 167772160);
  // wqbf region (2 MB) is dead after Q-proj; reuse for rowsum buffers:
  float* pbuf = (float*)(ws + 167772160);            // [8][8][2048] partials
  float* rinv = (float*)(ws + 167772160 + 524288);   // [8][2048] 1/rowsum

  // 1. fused prep: converts + V transpose (one launch)
  prep_kernel<<<6272, 256, 0, stream>>>(x, keys, Wq, vals, xbf, kbf, wqbf, vt);

  // 2. Q = x @ Wq^T + bq   (M=16384, N=1024, K=1024) grid 4x64 = 256
  gemm_bt<0><<<256, 512, 0, stream>>>(
      xbf, wqbf, qbf, bq, nullptr, DM_, DM_, 0, 0, 0, 0, 2, 6);

  // 3. p_unnorm = exp(Q @ K^T / 32 + mask), + rowsum partials
  gemm_bt<1><<<512, 512, 0, stream>>>(
      qbf, kbf, logits, mask, pbuf, LK_, DM_,
      (long)LQ_ * DM_, (long)LK_ * DM_, (long)LQ_ * LK_, LK_, 3, 3);

  // 4. rinv = 1 / rowsum
  rowsum_inv_kernel<<<64, 256, 0, stream>>>(pbuf, rinv);

  // 5. out = (P @ Vt^T) * rinv[row]  (per batch M=2048, N=1024, K=2048)
  gemm_bt<2><<<256, 512, 0, stream>>>(
      logits, vt, out, rinv, nullptr, DM_, LK_,
      (long)LQ_ * LK_, (long)DM_ * LK_, (long)LQ_ * DM_, 0, 2, 3);
}